// Round 1
// baseline (506.237 us; speedup 1.0000x reference)
//
#include <hip/hip_runtime.h>
#include <cstdint>

// ---------------------------------------------------------------------------
// SS-MSA fused implementation.
// Key identity: grid_shift(sim) with sim = SCALE*Q K^T + pos factorizes:
//   shifted[i,j] = SCALE*( q_{i-1}.k_{j-1} + q~_i . k~_j ) + P[i,j]
// where q~_i = wy0*q_{y0}+wy1*q_{y1}, k~_j = wx0*k_{x0}+wx1*k_{x1}
// and P is the same shift-transform applied to pos (per-batch, precomputed).
// => both branches are plain fused attention with 56-dim augmented Q/K + bias.
//
// Workspace layout (floats), total 34,127,904 f = ~136.5 MB (ws_size must cover):
//   q_w  [8][256][64][56]   @ 0
//   k_w                      @ 7340032
//   v_w                      @ 14680064
//   ssum [8][256][64][56]    @ 22020096   (reused as attn_out after conv1)
//   c1o  [2][8][256][64][16] @ 29360128
//   part [16][64][16]        @ 33554432
//   shif [16][2]             @ 33570816
//   P1T  [8][64j][64i]       @ 33570848
//   P2T  [8][256j][256i]     @ 33603616
// ---------------------------------------------------------------------------

#define SCALE_ 0.18898223650461364f  // 28^-0.5

__device__ __forceinline__ void coords_(int idx, int S, float s,
                                        int& i0, int& i1, float& w0, float& w1) {
    float g = -1.0f + 2.0f * (float)idx / (float)(S - 1);
    float c = (g + s * 2.0f / (float)S + 1.0f) * 0.5f * (float)(S - 1);
    float span = (float)(S - 1);
    c = fabsf(c);
    c = fmodf(c, 2.0f * span);
    if (c > span) c = 2.0f * span - c;
    int f = (int)floorf(c);
    f = max(0, min(f, S - 1));
    i0 = f;
    i1 = min(f + 1, S - 1);
    w1 = c - (float)f;
    w0 = 1.0f - w1;
}

// ------------------------------- K1: QKV GEMM ------------------------------
template <int RS, int C0>
__device__ __forceinline__ void qkv_chunk(const float* xrow, const float* __restrict__ W,
                                          float* __restrict__ outp, float* ss) {
    float acc[28];
#pragma unroll
    for (int c = 0; c < 28; ++c) acc[c] = 0.f;
    for (int d = 0; d < 56; ++d) {
        float xv = xrow[d];
        const float4* wr = (const float4*)(W + d * RS + C0);
#pragma unroll
        for (int k = 0; k < 7; ++k) {
            float4 w = wr[k];
            acc[4 * k + 0] += xv * w.x;
            acc[4 * k + 1] += xv * w.y;
            acc[4 * k + 2] += xv * w.z;
            acc[4 * k + 3] += xv * w.w;
        }
    }
    float4* op = (float4*)outp;
#pragma unroll
    for (int k = 0; k < 7; ++k)
        op[k] = make_float4(acc[4 * k + 0], acc[4 * k + 1], acc[4 * k + 2], acc[4 * k + 3]);
#pragma unroll
    for (int c = 0; c < 28; ++c) ss[c] += acc[c];
}

__global__ __launch_bounds__(256) void k_qkv(const float* __restrict__ x,
                                             const float* __restrict__ Wq,
                                             const float* __restrict__ Wkv,
                                             float* __restrict__ q_w, float* __restrict__ k_w,
                                             float* __restrict__ v_w, float* __restrict__ ssum) {
    __shared__ __align__(16) float xlds[256 * 57];  // per-thread x row (runtime-indexed -> LDS)
    int tid = threadIdx.x;
    int pix = blockIdx.x * 256 + tid;
    int b = pix >> 14;
    int rem = pix & 16383;
    int hh = rem >> 7;
    int ww = rem & 127;
    int n = ((hh >> 3) << 4) + (ww >> 3);
    int m = ((hh & 7) << 3) + (ww & 7);
    float* xrow = xlds + tid * 57;
    const float4* xp = (const float4*)(x + (size_t)pix * 56);
#pragma unroll
    for (int k = 0; k < 14; ++k) {
        float4 t = xp[k];
        xrow[4 * k + 0] = t.x;
        xrow[4 * k + 1] = t.y;
        xrow[4 * k + 2] = t.z;
        xrow[4 * k + 3] = t.w;
    }
    size_t ob = (((size_t)b * 256 + n) * 64 + m) * 56;
    float ssA[28], ssB[28];
#pragma unroll
    for (int c = 0; c < 28; ++c) { ssA[c] = 0.f; ssB[c] = 0.f; }
    qkv_chunk<56, 0>(xrow, Wq, q_w + ob, ssA);
    qkv_chunk<56, 28>(xrow, Wq, q_w + ob + 28, ssB);
    qkv_chunk<112, 0>(xrow, Wkv, k_w + ob, ssA);
    qkv_chunk<112, 28>(xrow, Wkv, k_w + ob + 28, ssB);
    qkv_chunk<112, 56>(xrow, Wkv, v_w + ob, ssA);
    qkv_chunk<112, 84>(xrow, Wkv, v_w + ob + 28, ssB);
    float4* sp = (float4*)(ssum + ob);
#pragma unroll
    for (int k = 0; k < 7; ++k)
        sp[k] = make_float4(ssA[4 * k + 0], ssA[4 * k + 1], ssA[4 * k + 2], ssA[4 * k + 3]);
#pragma unroll
    for (int k = 0; k < 7; ++k)
        sp[7 + k] = make_float4(ssB[4 * k + 0], ssB[4 * k + 1], ssB[4 * k + 2], ssB[4 * k + 3]);
}

// ------------------------------- K2: conv1 ---------------------------------
__global__ __launch_bounds__(256) void k_conv1(const float* __restrict__ ssum,
                                               const float* __restrict__ c1w,
                                               const float* __restrict__ c1b,
                                               float* __restrict__ c1o) {
    __shared__ __align__(16) float tile[6 * 66 * 29];
    __shared__ __align__(16) float wl[4032];
    int tid = threadIdx.x;
    int wg = blockIdx.x;
    int br = wg >> 9;
    int b = (wg >> 6) & 7;
    int nt = wg & 63;
    int n0 = nt * 4;
    for (int e = tid; e < 11088; e += 256) {
        int c = e % 28;
        int rest = e / 28;
        int mm = rest % 66;
        int nr = rest / 66;
        int n = n0 - 1 + nr;
        int m = mm - 1;
        float v = 0.f;
        if (n >= 0 && n < 256 && m >= 0 && m < 64)
            v = ssum[(((size_t)b * 256 + n) * 64 + m) * 56 + br * 28 + c];
        tile[(nr * 66 + mm) * 29 + c] = v;
    }
    for (int e = tid; e < 4032; e += 256) {
        int o = e & 15;
        int tap = e >> 4;
        wl[e] = c1w[o * 252 + tap];
    }
    __syncthreads();
    int ny = tid >> 6;
    int m = tid & 63;
    float acc[16];
#pragma unroll
    for (int o = 0; o < 16; ++o) acc[o] = 0.f;
    for (int c = 0; c < 28; ++c) {
#pragma unroll
        for (int ky = 0; ky < 3; ++ky) {
#pragma unroll
            for (int kx = 0; kx < 3; ++kx) {
                float iv = tile[((ny + ky) * 66 + (m + kx)) * 29 + c];
                const float4* wp = (const float4*)(wl + (c * 9 + ky * 3 + kx) * 16);
                float4 w0 = wp[0], w1 = wp[1], w2 = wp[2], w3 = wp[3];
                acc[0] += iv * w0.x;  acc[1] += iv * w0.y;  acc[2] += iv * w0.z;  acc[3] += iv * w0.w;
                acc[4] += iv * w1.x;  acc[5] += iv * w1.y;  acc[6] += iv * w1.z;  acc[7] += iv * w1.w;
                acc[8] += iv * w2.x;  acc[9] += iv * w2.y;  acc[10] += iv * w2.z; acc[11] += iv * w2.w;
                acc[12] += iv * w3.x; acc[13] += iv * w3.y; acc[14] += iv * w3.z; acc[15] += iv * w3.w;
            }
        }
    }
    float4 b0 = *(const float4*)(c1b + 0);
    float4 b1 = *(const float4*)(c1b + 4);
    float4 b2 = *(const float4*)(c1b + 8);
    float4 b3 = *(const float4*)(c1b + 12);
    size_t ob = (((size_t)(br * 8 + b) * 16384) + (size_t)(n0 + ny) * 64 + m) * 16;
    float4* op = (float4*)(c1o + ob);
    op[0] = make_float4(fmaxf(acc[0] + b0.x, 0.f), fmaxf(acc[1] + b0.y, 0.f),
                        fmaxf(acc[2] + b0.z, 0.f), fmaxf(acc[3] + b0.w, 0.f));
    op[1] = make_float4(fmaxf(acc[4] + b1.x, 0.f), fmaxf(acc[5] + b1.y, 0.f),
                        fmaxf(acc[6] + b1.z, 0.f), fmaxf(acc[7] + b1.w, 0.f));
    op[2] = make_float4(fmaxf(acc[8] + b2.x, 0.f), fmaxf(acc[9] + b2.y, 0.f),
                        fmaxf(acc[10] + b2.z, 0.f), fmaxf(acc[11] + b2.w, 0.f));
    op[3] = make_float4(fmaxf(acc[12] + b3.x, 0.f), fmaxf(acc[13] + b3.y, 0.f),
                        fmaxf(acc[14] + b3.z, 0.f), fmaxf(acc[15] + b3.w, 0.f));
}

// ------------------------- K3: conv2 + pooled partials ---------------------
__global__ __launch_bounds__(256) void k_conv2(const float* __restrict__ c1o,
                                               const float* __restrict__ c2w,
                                               const float* __restrict__ c2b,
                                               float* __restrict__ part) {
    __shared__ __align__(16) float tile[6 * 66 * 17];
    __shared__ __align__(16) float wl[2304];
    __shared__ float pbuf[4][16];
    int tid = threadIdx.x;
    int wg = blockIdx.x;
    int br = wg >> 9;
    int b = (wg >> 6) & 7;
    int nt = wg & 63;
    int n0 = nt * 4;
    for (int e = tid; e < 6336; e += 256) {
        int c = e & 15;
        int rest = e >> 4;
        int mm = rest % 66;
        int nr = rest / 66;
        int n = n0 - 1 + nr;
        int m = mm - 1;
        float v = 0.f;
        if (n >= 0 && n < 256 && m >= 0 && m < 64)
            v = c1o[(((size_t)(br * 8 + b) * 16384) + (size_t)n * 64 + m) * 16 + c];
        tile[(nr * 66 + mm) * 17 + c] = v;
    }
    for (int e = tid; e < 2304; e += 256) {
        int o = e & 15;
        int tap = e >> 4;
        wl[e] = c2w[o * 144 + tap];
    }
    __syncthreads();
    int ny = tid >> 6;
    int m = tid & 63;
    float acc[16];
#pragma unroll
    for (int o = 0; o < 16; ++o) acc[o] = 0.f;
    for (int c = 0; c < 16; ++c) {
#pragma unroll
        for (int ky = 0; ky < 3; ++ky) {
#pragma unroll
            for (int kx = 0; kx < 3; ++kx) {
                float iv = tile[((ny + ky) * 66 + (m + kx)) * 17 + c];
                const float4* wp = (const float4*)(wl + (c * 9 + ky * 3 + kx) * 16);
                float4 w0 = wp[0], w1 = wp[1], w2 = wp[2], w3 = wp[3];
                acc[0] += iv * w0.x;  acc[1] += iv * w0.y;  acc[2] += iv * w0.z;  acc[3] += iv * w0.w;
                acc[4] += iv * w1.x;  acc[5] += iv * w1.y;  acc[6] += iv * w1.z;  acc[7] += iv * w1.w;
                acc[8] += iv * w2.x;  acc[9] += iv * w2.y;  acc[10] += iv * w2.z; acc[11] += iv * w2.w;
                acc[12] += iv * w3.x; acc[13] += iv * w3.y; acc[14] += iv * w3.z; acc[15] += iv * w3.w;
            }
        }
    }
    int lane = tid & 63;
    int wid = tid >> 6;
#pragma unroll
    for (int o = 0; o < 16; ++o) {
        float s = fmaxf(acc[o] + c2b[o], 0.f);
#pragma unroll
        for (int msk = 1; msk < 64; msk <<= 1) s += __shfl_xor(s, msk);
        if (lane == 0) pbuf[wid][o] = s;
    }
    __syncthreads();
    if (tid < 16) {
        float s = pbuf[0][tid] + pbuf[1][tid] + pbuf[2][tid] + pbuf[3][tid];
        part[(((size_t)(br * 8 + b)) * 64 + nt) * 16 + tid] = s;
    }
}

// ------------------------- K4: reduce + FC -> shifts -----------------------
__global__ void k_fc(const float* __restrict__ part, const float* __restrict__ f1w,
                     const float* __restrict__ f1b, const float* __restrict__ f2w,
                     const float* __restrict__ f2b, float* __restrict__ shif) {
    __shared__ float sb[16][16];
    int t = threadIdx.x;
    int combo = t >> 4;
    int o = t & 15;
    float s = 0.f;
    for (int nt = 0; nt < 64; ++nt) s += part[((size_t)combo * 64 + nt) * 16 + o];
    sb[combo][o] = s * (1.0f / 16384.0f);
    __syncthreads();
    if (t < 16) {
        float p0 = f1b[0], p1 = f1b[1], rg = f2b[0];
        for (int oo = 0; oo < 16; ++oo) {
            float sv = sb[t][oo];
            p0 += sv * f1w[oo * 2 + 0];
            p1 += sv * f1w[oo * 2 + 1];
            rg += sv * f2w[oo];
        }
        shif[t * 2 + 0] = rg * tanhf(p0);
        shif[t * 2 + 1] = rg * tanhf(p1);
    }
}

// ------------------------- K5a/b: shifted pos precompute -------------------
__global__ __launch_bounds__(256) void k_pos1(const float* __restrict__ pos1,
                                              const float* __restrict__ shif,
                                              float* __restrict__ P1T) {
    int b = blockIdx.x;
    float sx = shif[b * 2 + 0];
    float sy = shif[b * 2 + 1];
    for (int e = threadIdx.x; e < 4096; e += 256) {
        int j = e >> 6;
        int i = e & 63;
        int y0, y1, x0, x1;
        float wy0, wy1, wx0, wx1;
        coords_(i, 64, sy, y0, y1, wy0, wy1);
        coords_(j, 64, sx, x0, x1, wx0, wx1);
        float v = pos1[((i - 1) & 63) * 64 + ((j - 1) & 63)] +
                  wy0 * (wx0 * pos1[y0 * 64 + x0] + wx1 * pos1[y0 * 64 + x1]) +
                  wy1 * (wx0 * pos1[y1 * 64 + x0] + wx1 * pos1[y1 * 64 + x1]);
        P1T[(size_t)b * 4096 + j * 64 + i] = v;
    }
}

__global__ __launch_bounds__(256) void k_pos2(const float* __restrict__ pos2,
                                              const float* __restrict__ shif,
                                              float* __restrict__ P2T) {
    int wg = blockIdx.x;
    int b = wg >> 8;
    int j = wg & 255;
    float sx = shif[16 + b * 2 + 0];
    float sy = shif[16 + b * 2 + 1];
    int i = threadIdx.x;
    int y0, y1, x0, x1;
    float wy0, wy1, wx0, wx1;
    coords_(i, 256, sy, y0, y1, wy0, wy1);
    coords_(j, 256, sx, x0, x1, wx0, wx1);
    float v = pos2[((i - 1) & 255) * 256 + ((j - 1) & 255)] +
              wy0 * (wx0 * pos2[y0 * 256 + x0] + wx1 * pos2[y0 * 256 + x1]) +
              wy1 * (wx0 * pos2[y1 * 256 + x0] + wx1 * pos2[y1 * 256 + x1]);
    P2T[(size_t)b * 65536 + (size_t)j * 256 + i] = v;
}

// --------------------- K6: branch-1 window attention (64x64) ---------------
__global__ __launch_bounds__(256) void k_attn1(const float* __restrict__ q_w,
                                               const float* __restrict__ k_w,
                                               const float* __restrict__ v_w,
                                               const float* __restrict__ P1T,
                                               const float* __restrict__ shif,
                                               float* __restrict__ aout) {
    __shared__ __align__(16) float rawq[1792];
    __shared__ __align__(16) float rawk[1792];
    __shared__ __align__(16) float rawv[1792];
    __shared__ __align__(16) float augu[7168];  // augqT[56][64] | augkT[56][64]; pT[64][68] overlays
    float* augqT = augu;
    float* augkT = augu + 3584;
    float* pT = augu;
    int tid = threadIdx.x;
    int wg = blockIdx.x;
    int b = wg >> 8;
    int n = wg & 255;
    size_t base = (((size_t)b * 256 + n) * 64) * 56;
    for (int e = tid; e < 1792; e += 256) {
        int r = e / 28;
        int c = e - r * 28;
        size_t g = base + (size_t)r * 56 + c;
        rawq[e] = q_w[g];
        rawk[e] = k_w[g];
        rawv[e] = v_w[g];
    }
    __syncthreads();
    float sx = shif[b * 2 + 0];
    float sy = shif[b * 2 + 1];
    {
        int i = tid & 63;
        int dc = tid >> 6;
        int y0, y1;
        float wy0, wy1;
        coords_(i, 64, sy, y0, y1, wy0, wy1);
        int rm = (i - 1) & 63;
        for (int d = dc * 14; d < dc * 14 + 14; ++d) {
            float v;
            if (d < 28) v = SCALE_ * rawq[rm * 28 + d];
            else {
                int c = d - 28;
                v = SCALE_ * (wy0 * rawq[y0 * 28 + c] + wy1 * rawq[y1 * 28 + c]);
            }
            augqT[d * 64 + i] = v;
        }
        int x0, x1;
        float wx0, wx1;
        coords_(i, 64, sx, x0, x1, wx0, wx1);
        for (int d = dc * 14; d < dc * 14 + 14; ++d) {
            float v;
            if (d < 28) v = rawk[rm * 28 + d];
            else {
                int c = d - 28;
                v = wx0 * rawk[x0 * 28 + c] + wx1 * rawk[x1 * 28 + c];
            }
            augkT[d * 64 + i] = v;
        }
    }
    __syncthreads();
    int ig = tid >> 4, jg = tid & 15;
    int i0 = ig * 4, j0 = jg * 4;
    float p[4][4];
#pragma unroll
    for (int jj = 0; jj < 4; ++jj) {
        float4 t = *(const float4*)(P1T + (size_t)b * 4096 + (size_t)(j0 + jj) * 64 + i0);
        p[0][jj] = t.x; p[1][jj] = t.y; p[2][jj] = t.z; p[3][jj] = t.w;
    }
    for (int d = 0; d < 56; ++d) {
        float4 aq = *(const float4*)(augqT + d * 64 + i0);
        float4 ak = *(const float4*)(augkT + d * 64 + j0);
        float aqv[4] = {aq.x, aq.y, aq.z, aq.w};
        float akv[4] = {ak.x, ak.y, ak.z, ak.w};
#pragma unroll
        for (int r = 0; r < 4; ++r)
#pragma unroll
            for (int jj = 0; jj < 4; ++jj) p[r][jj] += aqv[r] * akv[jj];
    }
    float inv[4];
#pragma unroll
    for (int r = 0; r < 4; ++r) {
        float mx = fmaxf(fmaxf(p[r][0], p[r][1]), fmaxf(p[r][2], p[r][3]));
#pragma unroll
        for (int msk = 1; msk < 16; msk <<= 1) mx = fmaxf(mx, __shfl_xor(mx, msk));
        float s = 0.f;
#pragma unroll
        for (int jj = 0; jj < 4; ++jj) {
            p[r][jj] = __expf(p[r][jj] - mx);
            s += p[r][jj];
        }
#pragma unroll
        for (int msk = 1; msk < 16; msk <<= 1) s += __shfl_xor(s, msk);
        inv[r] = 1.0f / s;
    }
    __syncthreads();  // aug reads done; pT overlays augu
#pragma unroll
    for (int jj = 0; jj < 4; ++jj)
        *(float4*)(pT + (size_t)(j0 + jj) * 68 + i0) =
            make_float4(p[0][jj] * inv[0], p[1][jj] * inv[1], p[2][jj] * inv[2], p[3][jj] * inv[3]);
    __syncthreads();
    if (tid < 224) {
        int rg = tid / 14;
        int cg = tid - rg * 14;
        float o00 = 0, o01 = 0, o10 = 0, o11 = 0, o20 = 0, o21 = 0, o30 = 0, o31 = 0;
        for (int j = 0; j < 64; ++j) {
            float4 pv = *(const float4*)(pT + (size_t)j * 68 + rg * 4);
            float2 vv = *(const float2*)(rawv + j * 28 + cg * 2);
            o00 += pv.x * vv.x; o01 += pv.x * vv.y;
            o10 += pv.y * vv.x; o11 += pv.y * vv.y;
            o20 += pv.z * vv.x; o21 += pv.z * vv.y;
            o30 += pv.w * vv.x; o31 += pv.w * vv.y;
        }
        size_t wb = base + (size_t)(rg * 4) * 56 + cg * 2;
        *(float2*)(aout + wb) = make_float2(o00, o01);
        *(float2*)(aout + wb + 56) = make_float2(o10, o11);
        *(float2*)(aout + wb + 112) = make_float2(o20, o21);
        *(float2*)(aout + wb + 168) = make_float2(o30, o31);
    }
}

// -------------------- K7: branch-2 cross-window attn (256x256) -------------
__global__ __launch_bounds__(256) void k_attn2(const float* __restrict__ q_w,
                                               const float* __restrict__ k_w,
                                               const float* __restrict__ v_w,
                                               const float* __restrict__ P2T,
                                               const float* __restrict__ shif,
                                               float* __restrict__ aout) {
    extern __shared__ __align__(16) float lds[];
    float* rawq = lds;            // 7168
    float* rawk = lds + 7168;     // 7168
    float* augqT = lds + 14336;   // 3584  [56][64]
    float* pT = lds;              // overlay: [256][68] = 17408 <= 17920
    float* augkT = lds + 17920;   // 14336 [56][256]
    float* rawv = lds + 32256;    // 7168
    int tid = threadIdx.x;
    int wg = blockIdx.x;
    int b = wg >> 8;
    int rem = wg & 255;
    int m = rem >> 2;
    int iq = rem & 3;
    size_t cb = (size_t)b * 917504 + (size_t)m * 56 + 28;  // + i*3584
    for (int e = tid; e < 7168; e += 256) {
        int r = e / 28;
        int c = e - r * 28;
        size_t g = cb + (size_t)r * 3584 + c;
        rawq[e] = q_w[g];
        rawk[e] = k_w[g];
        rawv[e] = v_w[g];
    }
    __syncthreads();
    float sx = shif[16 + b * 2 + 0];
    float sy = shif[16 + b * 2 + 1];
    {
        int ii = tid & 63;
        int dc = tid >> 6;
        int i = iq * 64 + ii;
        int y0, y1;
        float wy0, wy1;
        coords_(i, 256, sy, y0, y1, wy0, wy1);
        int rm = (i - 1) & 255;
        for (int d = dc * 14; d < dc * 14 + 14; ++d) {
            float v;
            if (d < 28) v = SCALE_ * rawq[rm * 28 + d];
            else {
                int c = d - 28;
                v = SCALE_ * (wy0 * rawq[y0 * 28 + c] + wy1 * rawq[y1 * 28 + c]);
            }
            augqT[d * 64 + ii] = v;
        }
    }
    {
        int j = tid;
        int x0, x1;
        float wx0, wx1;
        coords_(j, 256, sx, x0, x1, wx0, wx1);
        int rm = (j - 1) & 255;
        for (int d = 0; d < 56; ++d) {
            float v;
            if (d < 28) v = rawk[rm * 28 + d];
            else {
                int c = d - 28;
                v = wx0 * rawk[x0 * 28 + c] + wx1 * rawk[x1 * 28 + c];
            }
            augkT[d * 256 + j] = v;
        }
    }
    __syncthreads();
    int ig = tid >> 4, jg = tid & 15;
    int ii0 = ig * 4, j0 = jg * 16;
    float p[4][16];
#pragma unroll
    for (int jj = 0; jj < 16; ++jj) {
        float4 t = *(const float4*)(P2T + (size_t)b * 65536 + (size_t)(j0 + jj) * 256 + iq * 64 + ii0);
        p[0][jj] = t.x; p[1][jj] = t.y; p[2][jj] = t.z; p[3][jj] = t.w;
    }
    for (int d = 0; d < 56; ++d) {
        float4 aq = *(const float4*)(augqT + d * 64 + ii0);
        float aqv[4] = {aq.x, aq.y, aq.z, aq.w};
        const float4* kp = (const float4*)(augkT + d * 256 + j0);
        float4 k0 = kp[0], k1 = kp[1], k2 = kp[2], k3 = kp[3];
        float akv[16] = {k0.x, k0.y, k0.z, k0.w, k1.x, k1.y, k1.z, k1.w,
                         k2.x, k2.y, k2.z, k2.w, k3.x, k3.y, k3.z, k3.w};
#pragma unroll
        for (int r = 0; r < 4; ++r)
#pragma unroll
            for (int jj = 0; jj < 16; ++jj) p[r][jj] += aqv[r] * akv[jj];
    }
    float inv[4];
#pragma unroll
    for (int r = 0; r < 4; ++r) {
        float mx = p[r][0];
#pragma unroll
        for (int jj = 1; jj < 16; ++jj) mx = fmaxf(mx, p[r][jj]);
#pragma unroll
        for (int msk = 1; msk < 16; msk <<= 1) mx = fmaxf(mx, __shfl_xor(mx, msk));
        float s = 0.f;
#pragma unroll
        for (int jj = 0; jj < 16; ++jj) {
            p[r][jj] = __expf(p[r][jj] - mx);
            s += p[r][jj];
        }
#pragma unroll
        for (int msk = 1; msk < 16; msk <<= 1) s += __shfl_xor(s, msk);
        inv[r] = 1.0f / s;
    }
    __syncthreads();  // sim reads done; pT overlays rawq/rawk/augqT
#pragma unroll
    for (int jj = 0; jj < 16; ++jj)
        *(float4*)(pT + (size_t)(j0 + jj) * 68 + ii0) =
            make_float4(p[0][jj] * inv[0], p[1][jj] * inv[1], p[2][jj] * inv[2], p[3][jj] * inv[3]);
    __syncthreads();
    if (tid < 224) {
        int rg = tid / 14;
        int cg = tid - rg * 14;
        float o00 = 0, o01 = 0, o10 = 0, o11 = 0, o20 = 0, o21 = 0, o30 = 0, o31 = 0;
        for (int j = 0; j < 256; ++j) {
            float4 pv = *(const float4*)(pT + (size_t)j * 68 + rg * 4);
            float2 vv = *(const float2*)(rawv + j * 28 + cg * 2);
            o00 += pv.x * vv.x; o01 += pv.x * vv.y;
            o10 += pv.y * vv.x; o11 += pv.y * vv.y;
            o20 += pv.z * vv.x; o21 += pv.z * vv.y;
            o30 += pv.w * vv.x; o31 += pv.w * vv.y;
        }
        size_t wb = (((size_t)b * 256 + iq * 64 + rg * 4) * 64 + m) * 56 + 28 + cg * 2;
        *(float2*)(aout + wb) = make_float2(o00, o01);
        *(float2*)(aout + wb + 3584) = make_float2(o10, o11);
        *(float2*)(aout + wb + 7168) = make_float2(o20, o21);
        *(float2*)(aout + wb + 10752) = make_float2(o30, o31);
    }
}

// ----------------------- K8: output projection + unwindow ------------------
template <int C0>
__device__ __forceinline__ void out_chunk(const float* xrow, const float* __restrict__ W,
                                          const float* __restrict__ bout, float* __restrict__ dst) {
    float acc[28];
#pragma unroll
    for (int c = 0; c < 28; ++c) acc[c] = 0.f;
    for (int d = 0; d < 56; ++d) {
        float xv = xrow[d];
        const float4* wr = (const float4*)(W + d * 56 + C0);
#pragma unroll
        for (int k = 0; k < 7; ++k) {
            float4 w = wr[k];
            acc[4 * k + 0] += xv * w.x;
            acc[4 * k + 1] += xv * w.y;
            acc[4 * k + 2] += xv * w.z;
            acc[4 * k + 3] += xv * w.w;
        }
    }
    float4* op = (float4*)(dst + C0);
#pragma unroll
    for (int k = 0; k < 7; ++k) {
        float4 bb = *(const float4*)(bout + C0 + 4 * k);
        op[k] = make_float4(acc[4 * k + 0] + bb.x, acc[4 * k + 1] + bb.y,
                            acc[4 * k + 2] + bb.z, acc[4 * k + 3] + bb.w);
    }
}

__global__ __launch_bounds__(256) void k_out(const float* __restrict__ aout,
                                             const float* __restrict__ Wout,
                                             const float* __restrict__ bout,
                                             float* __restrict__ out) {
    __shared__ __align__(16) float xlds[256 * 57];
    int tid = threadIdx.x;
    int pix = blockIdx.x * 256 + tid;
    int b = pix >> 14;
    int r2 = pix & 16383;
    int n = r2 >> 6;
    int m = r2 & 63;
    float* xrow = xlds + tid * 57;
    const float4* ap = (const float4*)(aout + (size_t)pix * 56);
#pragma unroll
    for (int k = 0; k < 14; ++k) {
        float4 t = ap[k];
        xrow[4 * k + 0] = t.x;
        xrow[4 * k + 1] = t.y;
        xrow[4 * k + 2] = t.z;
        xrow[4 * k + 3] = t.w;
    }
    int h = ((n >> 4) << 3) + (m >> 3);
    int w = ((n & 15) << 3) + (m & 7);
    float* dst = out + (((size_t)b * 128 + h) * 128 + w) * 56;
    out_chunk<0>(xrow, Wout, bout, dst);
    out_chunk<28>(xrow, Wout, bout, dst);
}

// ---------------------------------------------------------------------------
extern "C" void kernel_launch(void* const* d_in, const int* in_sizes, int n_in,
                              void* d_out, int out_size, void* d_ws, size_t ws_size,
                              hipStream_t stream) {
    const float* x = (const float*)d_in[0];
    const float* pos1 = (const float*)d_in[1];
    const float* pos2 = (const float*)d_in[2];
    const float* Wq = (const float*)d_in[3];
    const float* Wkv = (const float*)d_in[4];
    const float* Wout = (const float*)d_in[5];
    const float* bout = (const float*)d_in[6];
    const float* c1w = (const float*)d_in[7];
    const float* c1b = (const float*)d_in[8];
    const float* c2w = (const float*)d_in[9];
    const float* c2b = (const float*)d_in[10];
    const float* f1w = (const float*)d_in[11];
    const float* f1b = (const float*)d_in[12];
    const float* f2w = (const float*)d_in[13];
    const float* f2b = (const float*)d_in[14];

    float* ws = (float*)d_ws;
    float* q_w = ws;
    float* k_w = q_w + 7340032;
    float* v_w = k_w + 7340032;
    float* ssum = v_w + 7340032;
    float* aout = ssum;  // reuse after conv1 consumed ssum
    float* c1o = ssum + 7340032;
    float* part = c1o + 4194304;
    float* shif = part + 16384;
    float* P1T = shif + 32;
    float* P2T = P1T + 32768;
    float* outp = (float*)d_out;

    (void)hipFuncSetAttribute((const void*)k_attn2,
                              hipFuncAttributeMaxDynamicSharedMemorySize, 157696);

    k_qkv<<<512, 256, 0, stream>>>(x, Wq, Wkv, q_w, k_w, v_w, ssum);
    k_conv1<<<1024, 256, 0, stream>>>(ssum, c1w, c1b, c1o);
    k_conv2<<<1024, 256, 0, stream>>>(c1o, c2w, c2b, part);
    k_fc<<<1, 256, 0, stream>>>(part, f1w, f1b, f2w, f2b, shif);
    k_pos1<<<8, 256, 0, stream>>>(pos1, shif, P1T);
    k_pos2<<<2048, 256, 0, stream>>>(pos2, shif, P2T);
    k_attn1<<<2048, 256, 0, stream>>>(q_w, k_w, v_w, P1T, shif, aout);
    k_attn2<<<2048, 256, 157696, stream>>>(q_w, k_w, v_w, P2T, shif, aout);
    k_out<<<512, 256, 0, stream>>>(aout, Wout, bout, outp);
}